// Round 1
// baseline (1343.656 us; speedup 1.0000x reference)
//
#include <hip/hip_runtime.h>
#include <math.h>

// Problem constants (fixed by the reference)
#define DIN   1024
#define NH    16
#define HD    64            // head dim (1024/16)
#define SEQ   1024
#define BG    4             // B*G
#define MROWS (BG*SEQ)      // 4096 flattened rows

// ---------------------------------------------------------------------------
// Generic GEMM: C[M,N] = A[M,K] @ W[N,K]^T + bias[N]  (all row-major fp32)
// Block 256 threads, 64x64 tile, BK=16, 4x4 accumulators per thread.
// ---------------------------------------------------------------------------
__global__ __launch_bounds__(256)
void gemm_awt(const float* __restrict__ A, const float* __restrict__ W,
              const float* __restrict__ bias, float* __restrict__ C,
              int M, int N, int K)
{
    __shared__ float As[16][65];   // [k][m], +1 pad breaks pow2 strides
    __shared__ float Ws[16][65];   // [k][n]
    const int tid = threadIdx.x;
    const int tx = tid & 15, ty = tid >> 4;
    const int row0 = blockIdx.y * 64;
    const int col0 = blockIdx.x * 64;

    float acc[4][4] = {};

    for (int k0 = 0; k0 < K; k0 += 16) {
        // Load 64x16 A tile (1024 floats, one float4 per thread)
        {
            const int e = tid * 4;
            const int m = e >> 4;          // 0..63
            const int k = e & 15;          // 0,4,8,12
            const float4 v = *(const float4*)(A + (size_t)(row0 + m) * K + k0 + k);
            As[k + 0][m] = v.x; As[k + 1][m] = v.y;
            As[k + 2][m] = v.z; As[k + 3][m] = v.w;
        }
        // Load 64x16 W tile (W is [N,K] row-major; tile over n=col0..+63)
        {
            const int e = tid * 4;
            const int n = e >> 4;
            const int k = e & 15;
            const float4 v = *(const float4*)(W + (size_t)(col0 + n) * K + k0 + k);
            Ws[k + 0][n] = v.x; Ws[k + 1][n] = v.y;
            Ws[k + 2][n] = v.z; Ws[k + 3][n] = v.w;
        }
        __syncthreads();
        #pragma unroll
        for (int k = 0; k < 16; ++k) {
            float a[4], b[4];
            #pragma unroll
            for (int i = 0; i < 4; ++i) a[i] = As[k][ty * 4 + i];
            #pragma unroll
            for (int j = 0; j < 4; ++j) b[j] = Ws[k][tx * 4 + j];
            #pragma unroll
            for (int i = 0; i < 4; ++i)
                #pragma unroll
                for (int j = 0; j < 4; ++j)
                    acc[i][j] += a[i] * b[j];
        }
        __syncthreads();
    }

    #pragma unroll
    for (int i = 0; i < 4; ++i) {
        const int r = row0 + ty * 4 + i;
        #pragma unroll
        for (int j = 0; j < 4; ++j) {
            const int c = col0 + tx * 4 + j;
            C[(size_t)r * N + c] = acc[i][j] + bias[c];
        }
    }
}

// ---------------------------------------------------------------------------
// Scores: S[bgh][n][m] = scale * sum_c Q[bg*SEQ+n][h*HD+c] * K[bg*SEQ+m][h*HD+c]
// Per-head GEMM, M=N=1024, K=64. Written (pre-softmax) into the probs output.
// grid (m_tiles=16, n_tiles=16, bgh=64)
// ---------------------------------------------------------------------------
__global__ __launch_bounds__(256)
void scores_kernel(const float* __restrict__ Q, const float* __restrict__ Kp,
                   float* __restrict__ S)
{
    __shared__ float As[16][65];   // [k][n] Q tile
    __shared__ float Bs[16][65];   // [k][m] K tile
    const int tid = threadIdx.x;
    const int tx = tid & 15, ty = tid >> 4;
    const int bgh = blockIdx.z;
    const int bg = bgh >> 4, h = bgh & 15;
    const int row0 = blockIdx.y * 64;  // n
    const int col0 = blockIdx.x * 64;  // m
    const float* Qh = Q  + (size_t)bg * SEQ * DIN + h * HD;
    const float* Kh = Kp + (size_t)bg * SEQ * DIN + h * HD;

    float acc[4][4] = {};

    for (int k0 = 0; k0 < HD; k0 += 16) {
        const int e = tid * 4;
        const int m = e >> 4;
        const int k = e & 15;
        {
            const float4 v = *(const float4*)(Qh + (size_t)(row0 + m) * DIN + k0 + k);
            As[k + 0][m] = v.x; As[k + 1][m] = v.y;
            As[k + 2][m] = v.z; As[k + 3][m] = v.w;
        }
        {
            const float4 v = *(const float4*)(Kh + (size_t)(col0 + m) * DIN + k0 + k);
            Bs[k + 0][m] = v.x; Bs[k + 1][m] = v.y;
            Bs[k + 2][m] = v.z; Bs[k + 3][m] = v.w;
        }
        __syncthreads();
        #pragma unroll
        for (int k = 0; k < 16; ++k) {
            float a[4], b[4];
            #pragma unroll
            for (int i = 0; i < 4; ++i) a[i] = As[k][ty * 4 + i];
            #pragma unroll
            for (int j = 0; j < 4; ++j) b[j] = Bs[k][tx * 4 + j];
            #pragma unroll
            for (int i = 0; i < 4; ++i)
                #pragma unroll
                for (int j = 0; j < 4; ++j)
                    acc[i][j] += a[i] * b[j];
        }
        __syncthreads();
    }

    const float scale = 0.125f;   // 1/sqrt(64)
    float* Sh = S + (size_t)bgh * SEQ * SEQ;
    #pragma unroll
    for (int i = 0; i < 4; ++i) {
        const int n = row0 + ty * 4 + i;
        #pragma unroll
        for (int j = 0; j < 4; ++j) {
            const int m = col0 + tx * 4 + j;
            Sh[(size_t)n * SEQ + m] = acc[i][j] * scale;
        }
    }
}

// ---------------------------------------------------------------------------
// Row softmax in-place, one 64-lane wave per 1024-wide row. 4 rows per block.
// ---------------------------------------------------------------------------
__global__ __launch_bounds__(256)
void softmax_kernel(float* __restrict__ P)
{
    const int tid = threadIdx.x;
    const int wave = tid >> 6, lane = tid & 63;
    const size_t row = (size_t)blockIdx.x * 4 + wave;
    float* p = P + row * SEQ;

    float v[16];
    float mx = -1e30f;
    #pragma unroll
    for (int i = 0; i < 16; ++i) { v[i] = p[lane + 64 * i]; mx = fmaxf(mx, v[i]); }
    #pragma unroll
    for (int o = 32; o; o >>= 1) mx = fmaxf(mx, __shfl_xor(mx, o));
    float s = 0.f;
    #pragma unroll
    for (int i = 0; i < 16; ++i) { v[i] = __expf(v[i] - mx); s += v[i]; }
    #pragma unroll
    for (int o = 32; o; o >>= 1) s += __shfl_xor(s, o);
    const float inv = 1.f / s;
    #pragma unroll
    for (int i = 0; i < 16; ++i) p[lane + 64 * i] = v[i] * inv;
}

// ---------------------------------------------------------------------------
// PV: R[bg*SEQ+n][h*HD+d] = sum_m P[bgh][n][m] * V[bg*SEQ+m][h*HD+d]
// Per-head GEMM, M=1024, N=64, K=1024. grid (n_tiles=16, bgh=64)
// ---------------------------------------------------------------------------
__global__ __launch_bounds__(256)
void pv_kernel(const float* __restrict__ P, const float* __restrict__ V,
               float* __restrict__ R)
{
    __shared__ float Ps[16][65];   // [k(m)][n]
    __shared__ float Vs[16][68];   // [k(m)][d], stride 68 keeps float4 stores aligned
    const int tid = threadIdx.x;
    const int tx = tid & 15, ty = tid >> 4;
    const int bgh = blockIdx.y;
    const int bg = bgh >> 4, h = bgh & 15;
    const int row0 = blockIdx.x * 64;  // n
    const float* Ph = P + (size_t)bgh * SEQ * SEQ;
    const float* Vh = V + (size_t)bg * SEQ * DIN + h * HD;

    float acc[4][4] = {};

    for (int k0 = 0; k0 < SEQ; k0 += 16) {
        {   // P tile: 64 n-rows x 16 m
            const int e = tid * 4;
            const int n = e >> 4;
            const int k = e & 15;
            const float4 v = *(const float4*)(Ph + (size_t)(row0 + n) * SEQ + k0 + k);
            Ps[k + 0][n] = v.x; Ps[k + 1][n] = v.y;
            Ps[k + 2][n] = v.z; Ps[k + 3][n] = v.w;
        }
        {   // V tile: 16 m-rows x 64 d (d contiguous)
            const int e = tid * 4;
            const int kr = e >> 6;         // 0..15
            const int d  = e & 63;         // multiple of 4
            const float4 v = *(const float4*)(Vh + (size_t)(k0 + kr) * DIN + d);
            *(float4*)&Vs[kr][d] = v;
        }
        __syncthreads();
        #pragma unroll
        for (int k = 0; k < 16; ++k) {
            float a[4], b[4];
            #pragma unroll
            for (int i = 0; i < 4; ++i) a[i] = Ps[k][ty * 4 + i];
            #pragma unroll
            for (int j = 0; j < 4; ++j) b[j] = Vs[k][tx * 4 + j];
            #pragma unroll
            for (int i = 0; i < 4; ++i)
                #pragma unroll
                for (int j = 0; j < 4; ++j)
                    acc[i][j] += a[i] * b[j];
        }
        __syncthreads();
    }

    #pragma unroll
    for (int i = 0; i < 4; ++i) {
        const int n = row0 + ty * 4 + i;
        #pragma unroll
        for (int j = 0; j < 4; ++j) {
            const int d = tx * 4 + j;
            R[(size_t)(bg * SEQ + n) * DIN + h * HD + d] = acc[i][j];
        }
    }
}

// ---------------------------------------------------------------------------
extern "C" void kernel_launch(void* const* d_in, const int* in_sizes, int n_in,
                              void* d_out, int out_size, void* d_ws, size_t ws_size,
                              hipStream_t stream)
{
    const float* xq  = (const float*)d_in[0];  // [4096,1024]
    const float* xkv = (const float*)d_in[1];  // [4096,1024]
    const float* Wq  = (const float*)d_in[2];
    const float* bq  = (const float*)d_in[3];
    const float* Wk  = (const float*)d_in[4];
    const float* bk  = (const float*)d_in[5];
    const float* Wv  = (const float*)d_in[6];
    const float* bv  = (const float*)d_in[7];
    const float* Wo  = (const float*)d_in[8];
    const float* bo  = (const float*)d_in[9];

    float* out0 = (float*)d_out;                             // [4096,1024]
    float* out1 = out0 + (size_t)MROWS * DIN;                // probs [64,1024,1024]

    // Workspace: Q, K, V, R each [4096,1024] fp32 (16 MiB each, 64 MiB total)
    float* Qw = (float*)d_ws;
    float* Kw = Qw + (size_t)MROWS * DIN;
    float* Vw = Kw + (size_t)MROWS * DIN;
    float* Rw = Vw + (size_t)MROWS * DIN;

    const dim3 blk(256);

    // Projections
    gemm_awt<<<dim3(16, 64), blk, 0, stream>>>(xq,  Wq, bq, Qw, MROWS, DIN, DIN);
    gemm_awt<<<dim3(16, 64), blk, 0, stream>>>(xkv, Wk, bk, Kw, MROWS, DIN, DIN);
    gemm_awt<<<dim3(16, 64), blk, 0, stream>>>(xkv, Wv, bv, Vw, MROWS, DIN, DIN);

    // Scores (pre-softmax) straight into probs output region
    scores_kernel<<<dim3(16, 16, 64), blk, 0, stream>>>(Qw, Kw, out1);

    // Row softmax in place (64*1024 rows, 4 rows/block)
    softmax_kernel<<<dim3(16384), blk, 0, stream>>>(out1);

    // P @ V per head
    pv_kernel<<<dim3(16, 64), blk, 0, stream>>>(out1, Vw, Rw);

    // Output projection
    gemm_awt<<<dim3(16, 64), blk, 0, stream>>>(Rw, Wo, bo, out0, MROWS, DIN, DIN);
}

// Round 2
// 685.078 us; speedup vs baseline: 1.9613x; 1.9613x over previous
//
#include <hip/hip_runtime.h>
#include <math.h>

// Problem constants
#define DIN   1024
#define NH    16
#define HD    64
#define SEQ   1024
#define BG    4
#define MROWS (BG*SEQ)      // 4096

typedef unsigned short u16;
typedef __attribute__((ext_vector_type(8))) short bf16x8;
typedef __attribute__((ext_vector_type(4))) float f32x4;

__device__ __forceinline__ u16 f2bf(float f) {
    unsigned u = __float_as_uint(f);
    u += 0x7fff + ((u >> 16) & 1);      // round-to-nearest-even
    return (u16)(u >> 16);
}

// ---------------------------------------------------------------------------
// fp32 -> bf16 elementwise convert (n multiple of 1024)
// ---------------------------------------------------------------------------
__global__ __launch_bounds__(256)
void convert_bf(const float* __restrict__ a, u16* __restrict__ o)
{
    const size_t i = ((size_t)blockIdx.x * 256 + threadIdx.x) * 4;
    const float4 v = *(const float4*)(a + i);
    ushort4 r;
    r.x = f2bf(v.x); r.y = f2bf(v.y); r.z = f2bf(v.z); r.w = f2bf(v.w);
    *(ushort4*)(o + i) = r;
}

// ---------------------------------------------------------------------------
// bf16 MFMA GEMM-BT: C[M,N] = A[M,K] @ W[N,K]^T + bias
// 128x128 tile, BK=32, 256 thr = 4 waves (2x2), wave tile 64x64 (4x4 MFMA
// 16x16x32). LDS rows padded to 40 bf16 (80 B) -> <=2-way bank aliasing.
// ---------------------------------------------------------------------------
template<int OUT_BF16>
__global__ __launch_bounds__(256)
void gemm_bt(const u16* __restrict__ A, int lda,
             const u16* __restrict__ W, int ldw,
             const float* __restrict__ bias,
             void* __restrict__ Cout, int ldc, int K)
{
    __shared__ u16 As[128][40];
    __shared__ u16 Ws[128][40];
    const int tid = threadIdx.x;
    const int wave = tid >> 6, lane = tid & 63;
    const int wm = wave >> 1, wn = wave & 1;
    const int q = lane >> 4, c = lane & 15;
    const int row0 = blockIdx.y * 128, col0 = blockIdx.x * 128;
    const int rs = tid >> 2, kg = (tid & 3) * 8;

    f32x4 acc[4][4];
    #pragma unroll
    for (int i = 0; i < 4; i++)
        #pragma unroll
        for (int j = 0; j < 4; j++) acc[i][j] = (f32x4){0.f, 0.f, 0.f, 0.f};

    for (int k0 = 0; k0 < K; k0 += 32) {
        *(float4*)&As[rs][kg]      = *(const float4*)(A + (size_t)(row0 + rs) * lda + k0 + kg);
        *(float4*)&As[rs + 64][kg] = *(const float4*)(A + (size_t)(row0 + rs + 64) * lda + k0 + kg);
        *(float4*)&Ws[rs][kg]      = *(const float4*)(W + (size_t)(col0 + rs) * ldw + k0 + kg);
        *(float4*)&Ws[rs + 64][kg] = *(const float4*)(W + (size_t)(col0 + rs + 64) * ldw + k0 + kg);
        __syncthreads();
        bf16x8 af[4], bfr[4];
        #pragma unroll
        for (int i = 0; i < 4; i++) af[i]  = *(const bf16x8*)&As[wm * 64 + i * 16 + c][q * 8];
        #pragma unroll
        for (int j = 0; j < 4; j++) bfr[j] = *(const bf16x8*)&Ws[wn * 64 + j * 16 + c][q * 8];
        #pragma unroll
        for (int i = 0; i < 4; i++)
            #pragma unroll
            for (int j = 0; j < 4; j++)
                acc[i][j] = __builtin_amdgcn_mfma_f32_16x16x32_bf16(af[i], bfr[j], acc[i][j], 0, 0, 0);
        __syncthreads();
    }

    float bv[4];
    #pragma unroll
    for (int j = 0; j < 4; j++) bv[j] = bias[col0 + wn * 64 + j * 16 + c];
    #pragma unroll
    for (int i = 0; i < 4; i++)
        #pragma unroll
        for (int r = 0; r < 4; r++) {
            const size_t row = row0 + wm * 64 + i * 16 + q * 4 + r;
            #pragma unroll
            for (int j = 0; j < 4; j++) {
                const int col = col0 + wn * 64 + j * 16 + c;
                const float v = acc[i][j][r] + bv[j];
                if (OUT_BF16) ((u16*)Cout)[row * ldc + col] = f2bf(v);
                else          ((float*)Cout)[row * ldc + col] = v;
            }
        }
}

// ---------------------------------------------------------------------------
// Scores: S[bgh][n][m] = 0.125 * Qh[n,:] . Kh[m,:]   (K=64, bf16 MFMA)
// Writes fp32 S into probs region + per-tile row max / sum-exp partials.
// grid (m_tiles=8, n_tiles=8, bgh=64)
// ---------------------------------------------------------------------------
__global__ __launch_bounds__(256)
void scores_mfma(const u16* __restrict__ Qbf, const u16* __restrict__ Kbf,
                 float* __restrict__ S,
                 float* __restrict__ m_p, float* __restrict__ l_p)
{
    __shared__ u16 As[128][40];
    __shared__ u16 Bs[128][40];
    __shared__ float red[128][2];
    const int tid = threadIdx.x;
    const int wave = tid >> 6, lane = tid & 63;
    const int wm = wave >> 1, wn = wave & 1;
    const int q = lane >> 4, c = lane & 15;
    const int bgh = blockIdx.z, bg = bgh >> 4, h = bgh & 15;
    const int n0 = blockIdx.y * 128, m0 = blockIdx.x * 128;
    const u16* Qh = Qbf + (size_t)bg * SEQ * DIN + h * HD;
    const u16* Kh = Kbf + (size_t)bg * SEQ * DIN + h * HD;
    const int rs = tid >> 2, kg = (tid & 3) * 8;

    f32x4 acc[4][4];
    #pragma unroll
    for (int i = 0; i < 4; i++)
        #pragma unroll
        for (int j = 0; j < 4; j++) acc[i][j] = (f32x4){0.f, 0.f, 0.f, 0.f};

    #pragma unroll
    for (int k0 = 0; k0 < HD; k0 += 32) {
        *(float4*)&As[rs][kg]      = *(const float4*)(Qh + (size_t)(n0 + rs) * DIN + k0 + kg);
        *(float4*)&As[rs + 64][kg] = *(const float4*)(Qh + (size_t)(n0 + rs + 64) * DIN + k0 + kg);
        *(float4*)&Bs[rs][kg]      = *(const float4*)(Kh + (size_t)(m0 + rs) * DIN + k0 + kg);
        *(float4*)&Bs[rs + 64][kg] = *(const float4*)(Kh + (size_t)(m0 + rs + 64) * DIN + k0 + kg);
        __syncthreads();
        bf16x8 af[4], bfr[4];
        #pragma unroll
        for (int i = 0; i < 4; i++) af[i]  = *(const bf16x8*)&As[wm * 64 + i * 16 + c][q * 8];
        #pragma unroll
        for (int j = 0; j < 4; j++) bfr[j] = *(const bf16x8*)&Bs[wn * 64 + j * 16 + c][q * 8];
        #pragma unroll
        for (int i = 0; i < 4; i++)
            #pragma unroll
            for (int j = 0; j < 4; j++)
                acc[i][j] = __builtin_amdgcn_mfma_f32_16x16x32_bf16(af[i], bfr[j], acc[i][j], 0, 0, 0);
        __syncthreads();
    }

    // scale in registers
    #pragma unroll
    for (int i = 0; i < 4; i++)
        #pragma unroll
        for (int j = 0; j < 4; j++) acc[i][j] *= 0.125f;

    // pass 1: per-row max over this 128-col tile (regs -> shfl -> LDS)
    float M16[4][4];
    #pragma unroll
    for (int i = 0; i < 4; i++)
        #pragma unroll
        for (int r = 0; r < 4; r++) {
            float mx = fmaxf(fmaxf(acc[i][0][r], acc[i][1][r]),
                             fmaxf(acc[i][2][r], acc[i][3][r]));
            mx = fmaxf(mx, __shfl_xor(mx, 1));
            mx = fmaxf(mx, __shfl_xor(mx, 2));
            mx = fmaxf(mx, __shfl_xor(mx, 4));
            mx = fmaxf(mx, __shfl_xor(mx, 8));
            if (c == 0) red[wm * 64 + i * 16 + q * 4 + r][wn] = mx;
        }
    __syncthreads();
    #pragma unroll
    for (int i = 0; i < 4; i++)
        #pragma unroll
        for (int r = 0; r < 4; r++) {
            const int rl = wm * 64 + i * 16 + q * 4 + r;
            M16[i][r] = fmaxf(red[rl][0], red[rl][1]);
        }
    __syncthreads();
    // pass 2: sum exp(s - M) from registers
    #pragma unroll
    for (int i = 0; i < 4; i++)
        #pragma unroll
        for (int r = 0; r < 4; r++) {
            float s = __expf(acc[i][0][r] - M16[i][r]) + __expf(acc[i][1][r] - M16[i][r])
                    + __expf(acc[i][2][r] - M16[i][r]) + __expf(acc[i][3][r] - M16[i][r]);
            s += __shfl_xor(s, 1);
            s += __shfl_xor(s, 2);
            s += __shfl_xor(s, 4);
            s += __shfl_xor(s, 8);
            if (c == 0) red[wm * 64 + i * 16 + q * 4 + r][wn] = s;
        }
    __syncthreads();
    if (wn == 0 && c == 0) {
        #pragma unroll
        for (int i = 0; i < 4; i++)
            #pragma unroll
            for (int r = 0; r < 4; r++) {
                const int rl = wm * 64 + i * 16 + q * 4 + r;
                const float l = red[rl][0] + red[rl][1];
                const size_t idx = ((size_t)bgh * SEQ + n0 + rl) * 8 + blockIdx.x;
                m_p[idx] = M16[i][r];
                l_p[idx] = l;
            }
    }

    // write fp32 pre-softmax S
    float* Sh = S + (size_t)bgh * SEQ * SEQ;
    #pragma unroll
    for (int i = 0; i < 4; i++)
        #pragma unroll
        for (int r = 0; r < 4; r++) {
            const size_t row = n0 + wm * 64 + i * 16 + q * 4 + r;
            #pragma unroll
            for (int j = 0; j < 4; j++)
                Sh[row * SEQ + m0 + wn * 64 + j * 16 + c] = acc[i][j][r];
        }
}

// ---------------------------------------------------------------------------
// Combine the 8 column-tile partials -> per-row M, 1/L
// ---------------------------------------------------------------------------
__global__ __launch_bounds__(256)
void reduce_ml(const float* __restrict__ m_p, const float* __restrict__ l_p,
               float* __restrict__ Mrow, float* __restrict__ invL)
{
    const size_t row = (size_t)blockIdx.x * 256 + threadIdx.x;   // 65536 rows
    float M = -1e30f;
    #pragma unroll
    for (int t = 0; t < 8; t++) M = fmaxf(M, m_p[row * 8 + t]);
    float L = 0.f;
    #pragma unroll
    for (int t = 0; t < 8; t++) L += l_p[row * 8 + t] * __expf(m_p[row * 8 + t] - M);
    Mrow[row] = M;
    invL[row] = 1.f / L;
}

// ---------------------------------------------------------------------------
// PV: reads S (fp32), computes p = exp(s-M)*invL, writes probs back in place,
// and accumulates R = p @ V via bf16 MFMA. Tile 128n x 64d, BK(m)=32.
// grid (n_tiles=8, bgh=64)
// ---------------------------------------------------------------------------
__global__ __launch_bounds__(256)
void pv_mfma(float* __restrict__ S, const u16* __restrict__ Vbf,
             const float* __restrict__ Mrow, const float* __restrict__ invL,
             u16* __restrict__ Rbf)
{
    __shared__ u16 Ps[128][40];
    __shared__ u16 Vs[64][40];
    __shared__ float Ms[128], Ls[128];
    const int tid = threadIdx.x;
    const int wave = tid >> 6, lane = tid & 63;
    const int wm = wave >> 1, wn = wave & 1;
    const int q = lane >> 4, c = lane & 15;
    const int bgh = blockIdx.y, bg = bgh >> 4, h = bgh & 15;
    const int n0 = blockIdx.x * 128;
    float* Sh = S + (size_t)bgh * SEQ * SEQ;
    const size_t rowbase = (size_t)bgh * SEQ + n0;

    if (tid < 128) { Ms[tid] = Mrow[rowbase + tid]; Ls[tid] = invL[rowbase + tid]; }
    __syncthreads();

    f32x4 acc[4][2];
    #pragma unroll
    for (int i = 0; i < 4; i++) { acc[i][0] = (f32x4){0.f,0.f,0.f,0.f}; acc[i][1] = (f32x4){0.f,0.f,0.f,0.f}; }

    for (int m0 = 0; m0 < SEQ; m0 += 32) {
        // stage P: load S, softmax-normalize, write probs back, bf16 -> LDS
        #pragma unroll
        for (int s4 = 0; s4 < 4; s4++) {
            const int nl = (tid >> 3) + s4 * 32;
            const int mg = (tid & 7) * 4;
            float* sp = Sh + (size_t)(n0 + nl) * SEQ + m0 + mg;
            const float4 sv = *(const float4*)sp;
            const float M = Ms[nl], L = Ls[nl];
            const float p0 = __expf(sv.x - M) * L;
            const float p1 = __expf(sv.y - M) * L;
            const float p2 = __expf(sv.z - M) * L;
            const float p3 = __expf(sv.w - M) * L;
            *(float4*)sp = make_float4(p0, p1, p2, p3);
            ushort4 pb; pb.x = f2bf(p0); pb.y = f2bf(p1); pb.z = f2bf(p2); pb.w = f2bf(p3);
            *(ushort4*)&Ps[nl][mg] = pb;
        }
        // stage V transposed: Vs[d][m]
        {
            const int mv = tid >> 3, dg = (tid & 7) * 8;
            const float4 vv = *(const float4*)(Vbf + (size_t)(bg * SEQ + m0 + mv) * DIN + h * HD + dg);
            const u16* vp = (const u16*)&vv;
            #pragma unroll
            for (int u = 0; u < 8; u++) Vs[dg + u][mv] = vp[u];
        }
        __syncthreads();
        bf16x8 af[4], bfv[2];
        #pragma unroll
        for (int i = 0; i < 4; i++) af[i]  = *(const bf16x8*)&Ps[wm * 64 + i * 16 + c][q * 8];
        #pragma unroll
        for (int j = 0; j < 2; j++) bfv[j] = *(const bf16x8*)&Vs[wn * 32 + j * 16 + c][q * 8];
        #pragma unroll
        for (int i = 0; i < 4; i++)
            #pragma unroll
            for (int j = 0; j < 2; j++)
                acc[i][j] = __builtin_amdgcn_mfma_f32_16x16x32_bf16(af[i], bfv[j], acc[i][j], 0, 0, 0);
        __syncthreads();
    }

    #pragma unroll
    for (int i = 0; i < 4; i++)
        #pragma unroll
        for (int r = 0; r < 4; r++) {
            const size_t row = (size_t)bg * SEQ + n0 + wm * 64 + i * 16 + q * 4 + r;
            #pragma unroll
            for (int j = 0; j < 2; j++) {
                const int d = wn * 32 + j * 16 + c;
                Rbf[row * DIN + h * HD + d] = f2bf(acc[i][j][r]);
            }
        }
}

// ---------------------------------------------------------------------------
extern "C" void kernel_launch(void* const* d_in, const int* in_sizes, int n_in,
                              void* d_out, int out_size, void* d_ws, size_t ws_size,
                              hipStream_t stream)
{
    const float* xq  = (const float*)d_in[0];
    const float* xkv = (const float*)d_in[1];
    const float* Wq  = (const float*)d_in[2];
    const float* bq  = (const float*)d_in[3];
    const float* Wk  = (const float*)d_in[4];
    const float* bk  = (const float*)d_in[5];
    const float* Wv  = (const float*)d_in[6];
    const float* bv  = (const float*)d_in[7];
    const float* Wo  = (const float*)d_in[8];
    const float* bo  = (const float*)d_in[9];

    float* out0 = (float*)d_out;
    float* out1 = out0 + (size_t)MROWS * DIN;   // probs region, 64*1024*1024 fp32

    // workspace layout (~60.5 MB)
    u16* xq_bf  = (u16*)d_ws;
    u16* xkv_bf = xq_bf  + (size_t)MROWS * DIN;
    u16* Wq_bf  = xkv_bf + (size_t)MROWS * DIN;
    u16* Wk_bf  = Wq_bf  + (size_t)DIN * DIN;
    u16* Wv_bf  = Wk_bf  + (size_t)DIN * DIN;
    u16* Wo_bf  = Wv_bf  + (size_t)DIN * DIN;
    u16* Qbf    = Wo_bf  + (size_t)DIN * DIN;
    u16* Kbf    = Qbf    + (size_t)MROWS * DIN;
    u16* Vbf    = Kbf    + (size_t)MROWS * DIN;
    u16* Rbf    = Vbf    + (size_t)MROWS * DIN;
    float* m_p  = (float*)(Rbf + (size_t)MROWS * DIN);
    float* l_p  = m_p  + (size_t)64 * SEQ * 8;
    float* Mrow = l_p  + (size_t)64 * SEQ * 8;
    float* invL = Mrow + (size_t)64 * SEQ;

    const dim3 blk(256);

    // fp32 -> bf16 converts
    convert_bf<<<dim3(4096), blk, 0, stream>>>(xq,  xq_bf);
    convert_bf<<<dim3(4096), blk, 0, stream>>>(xkv, xkv_bf);
    convert_bf<<<dim3(1024), blk, 0, stream>>>(Wq,  Wq_bf);
    convert_bf<<<dim3(1024), blk, 0, stream>>>(Wk,  Wk_bf);
    convert_bf<<<dim3(1024), blk, 0, stream>>>(Wv,  Wv_bf);
    convert_bf<<<dim3(1024), blk, 0, stream>>>(Wo,  Wo_bf);

    // projections (bf16 out)
    gemm_bt<1><<<dim3(8, 32), blk, 0, stream>>>(xq_bf,  DIN, Wq_bf, DIN, bq, Qbf, DIN, DIN);
    gemm_bt<1><<<dim3(8, 32), blk, 0, stream>>>(xkv_bf, DIN, Wk_bf, DIN, bk, Kbf, DIN, DIN);
    gemm_bt<1><<<dim3(8, 32), blk, 0, stream>>>(xkv_bf, DIN, Wv_bf, DIN, bv, Vbf, DIN, DIN);

    // scores + softmax partials
    scores_mfma<<<dim3(8, 8, 64), blk, 0, stream>>>(Qbf, Kbf, out1, m_p, l_p);
    reduce_ml<<<dim3(256), blk, 0, stream>>>(m_p, l_p, Mrow, invL);

    // probs (in place) + P@V
    pv_mfma<<<dim3(8, 64), blk, 0, stream>>>(out1, Vbf, Mrow, invL, Rbf);

    // output projection (fp32 out)
    gemm_bt<0><<<dim3(8, 32), blk, 0, stream>>>(Rbf, DIN, Wo_bf, DIN, bo, out0, DIN, DIN);
}